// Round 25
// baseline (498.263 us; speedup 1.0000x reference)
//
#include <hip/hip_runtime.h>
#include <hip/hip_bf16.h>
#include <math.h>

#define B_ 8
#define C_ 256
#define P_ 4096

typedef __bf16 bf16_t;
typedef __attribute__((ext_vector_type(8))) __bf16 bf16x8;
typedef __attribute__((ext_vector_type(4))) __bf16 bf16x4;
typedef __attribute__((ext_vector_type(4))) float f32x4;

// ---------------------------------------------------------------------------
// Channel-LN stats. TRANS=0: in[b][c][p]; TRANS=1: in[b][p][C] bf16 rows.
// TROUT=1 (TRANS=0, bf16 in): also write transposed copy outT[b*4096+p][256].
// ---------------------------------------------------------------------------
template<typename T, int TRANS, int TROUT>
__global__ __launch_bounds__(256)
void ln_stats_kernel(const T* __restrict__ in, float2* __restrict__ stats,
                     bf16_t* __restrict__ outT)
{
    __shared__ float sred[4][64];
    __shared__ float s2red[4][64];
    int tid = threadIdx.x;
    if (TRANS) {
        int wp = tid >> 2, cw = tid & 3;
        int gp = blockIdx.x * 64 + wp;
        const bf16_t* row = (const bf16_t*)in + (size_t)gp * 256 + cw * 64;
        float s = 0.f, s2 = 0.f;
        #pragma unroll
        for (int i = 0; i < 64; i += 8) {
            bf16x8 v = *reinterpret_cast<const bf16x8*>(&row[i]);
            #pragma unroll
            for (int j = 0; j < 8; ++j) {
                float f = (float)v[j]; s += f; s2 += f * f;
            }
        }
        sred[cw][wp] = s; s2red[cw][wp] = s2;
        __syncthreads();
        if (cw == 0) {
            s  = sred[0][wp]  + sred[1][wp]  + sred[2][wp]  + sred[3][wp];
            s2 = s2red[0][wp] + s2red[1][wp] + s2red[2][wp] + s2red[3][wp];
            float mu  = s * (1.f / 256.f);
            float var = s2 * (1.f / 256.f) - mu * mu;
            stats[gp] = make_float2(mu, 1.0f / sqrtf(var + 1e-5f));
        }
        return;
    }
    int wp = tid & 63, cw = tid >> 6;
    int gp = blockIdx.x * 64 + wp;
    int b  = gp >> 12, p = gp & 4095;
    size_t base = (size_t)b * 256 * 4096 + p;
    float s = 0.f, s2 = 0.f;
    bf16x8 chunk;
    #pragma unroll 8
    for (int cc = 0; cc < 64; ++cc) {
        float v = (float)in[base + (size_t)(cw * 64 + cc) * 4096];
        s += v; s2 += v * v;
        if (TROUT) {
            chunk[cc & 7] = (bf16_t)v;
            if ((cc & 7) == 7)
                *reinterpret_cast<bf16x8*>(
                    &outT[(size_t)gp * 256 + cw * 64 + (cc & ~7)]) = chunk;
        }
    }
    sred[cw][wp] = s; s2red[cw][wp] = s2;
    __syncthreads();
    if (cw == 0) {
        s  = sred[0][wp]  + sred[1][wp]  + sred[2][wp]  + sred[3][wp];
        s2 = s2red[0][wp] + s2red[1][wp] + s2red[2][wp] + s2red[3][wp];
        float mu  = s * (1.f / 256.f);
        float var = s2 * (1.f / 256.f) - mu * mu;
        stats[gp] = make_float2(mu, 1.0f / sqrtf(var + 1e-5f));
    }
}

// ---------------------------------------------------------------------------
// skip transpose: f32 [b][512][4096] -> bf16 [b][p][512], LDS 64x64 tile.
// ---------------------------------------------------------------------------
__global__ __launch_bounds__(256)
void skip_transpose_kernel(const float* __restrict__ in, bf16_t* __restrict__ outT)
{
    __shared__ bf16_t t[64 * 66];
    int p0 = blockIdx.x << 6;
    int c0 = blockIdx.y << 6;
    int b  = blockIdx.z;
    int tid = threadIdx.x;
    int pl = tid & 63, cq = tid >> 6;
    const float* src = in + ((size_t)b * 512 + c0) * 4096 + p0;
    #pragma unroll
    for (int i = 0; i < 16; ++i) {
        int cl = i * 4 + cq;
        t[pl * 66 + cl] = (bf16_t)src[(size_t)cl * 4096 + pl];
    }
    __syncthreads();
    int pw = tid >> 2, ch = tid & 3;
    bf16x8 v0 = *reinterpret_cast<const bf16x8*>(&t[pw * 66 + ch * 16]);
    bf16x8 v1 = *reinterpret_cast<const bf16x8*>(&t[pw * 66 + ch * 16 + 8]);
    bf16_t* dst = outT + ((size_t)b * 4096 + p0 + pw) * 512 + c0 + ch * 16;
    *reinterpret_cast<bf16x8*>(dst) = v0;
    *reinterpret_cast<bf16x8*>(dst + 8) = v1;
}

// ---------------------------------------------------------------------------
// Fused LN1 + q_shift + blend + 3-way mix, vectorized x8 along w.
// ---------------------------------------------------------------------------
__global__ __launch_bounds__(256)
void qshift_mix_kernel(const float* __restrict__ x, const float2* __restrict__ st1,
                       const float* __restrict__ mask,
                       const float* __restrict__ gw, const float* __restrict__ gb,
                       const float* __restrict__ mk_, const float* __restrict__ mv_,
                       const float* __restrict__ mr_,
                       bf16_t* __restrict__ xk, bf16_t* __restrict__ xv,
                       bf16_t* __restrict__ xr)
{
    int gid = blockIdx.x * 256 + threadIdx.x;
    int g = gid << 3;
    int p = g & 4095;
    int c = (g >> 12) & 255;
    int b = g >> 20;
    int h = p >> 6, w0 = p & 63;
    float gwc = gw[c], gbc = gb[c];
    int sbase = (b << 12) + p;

    float4 x0 = *reinterpret_cast<const float4*>(&x[g]);
    float4 x1 = *reinterpret_cast<const float4*>(&x[g + 4]);
    float xv8[8] = {x0.x, x0.y, x0.z, x0.w, x1.x, x1.y, x1.z, x1.w};
    float2 s8[8];
    #pragma unroll
    for (int i = 0; i < 4; ++i) {
        float4 t = *reinterpret_cast<const float4*>(&st1[sbase + i * 2]);
        s8[2 * i]     = make_float2(t.x, t.y);
        s8[2 * i + 1] = make_float2(t.z, t.w);
    }
    float xn8[8];
    #pragma unroll
    for (int i = 0; i < 8; ++i)
        xn8[i] = (xv8[i] - s8[i].x) * s8[i].y * gwc + gbc;

    float xs8[8];
    int quad = c >> 6;
    if (quad == 0) {
        xs8[0] = 0.f;
        if (w0 > 0) {
            float xm = x[g - 1]; float2 sm = st1[sbase - 1];
            xs8[0] = (xm - sm.x) * sm.y * gwc + gbc;
        }
        #pragma unroll
        for (int i = 1; i < 8; ++i) xs8[i] = xn8[i - 1];
    } else if (quad == 1) {
        #pragma unroll
        for (int i = 0; i < 7; ++i) xs8[i] = xn8[i + 1];
        xs8[7] = 0.f;
        if (w0 + 8 < 64) {
            float xp = x[g + 8]; float2 sp = st1[sbase + 8];
            xs8[7] = (xp - sp.x) * sp.y * gwc + gbc;
        }
    } else {
        int d = (quad == 2) ? -64 : 64;
        bool ok = (quad == 2) ? (h > 0) : (h < 63);
        if (ok) {
            float4 y0 = *reinterpret_cast<const float4*>(&x[g + d]);
            float4 y1 = *reinterpret_cast<const float4*>(&x[g + d + 4]);
            float yv8[8] = {y0.x, y0.y, y0.z, y0.w, y1.x, y1.y, y1.z, y1.w};
            #pragma unroll
            for (int i = 0; i < 4; ++i) {
                float4 t = *reinterpret_cast<const float4*>(&st1[sbase + d + i * 2]);
                float2 sa = make_float2(t.x, t.y), sb = make_float2(t.z, t.w);
                xs8[2 * i]     = (yv8[2 * i]     - sa.x) * sa.y * gwc + gbc;
                xs8[2 * i + 1] = (yv8[2 * i + 1] - sb.x) * sb.y * gwc + gbc;
            }
        } else {
            #pragma unroll
            for (int i = 0; i < 8; ++i) xs8[i] = 0.f;
        }
    }

    float4 m0 = *reinterpret_cast<const float4*>(&mask[sbase]);
    float4 m1 = *reinterpret_cast<const float4*>(&mask[sbase + 4]);
    float mm[8] = {m0.x, m0.y, m0.z, m0.w, m1.x, m1.y, m1.z, m1.w};
    float xsh8[8];
    #pragma unroll
    for (int i = 0; i < 8; ++i)
        xsh8[i] = mm[i] * xs8[i] + (1.f - mm[i]) * xn8[i];

    float ak = mk_[c], av = mv_[c], ar = mr_[c];
    bf16x8 ok_, ov_, or_;
    #pragma unroll
    for (int i = 0; i < 8; ++i) {
        ok_[i] = (bf16_t)(ak * xn8[i] + (1.f - ak) * xsh8[i]);
        ov_[i] = (bf16_t)(av * xn8[i] + (1.f - av) * xsh8[i]);
        or_[i] = (bf16_t)(ar * xn8[i] + (1.f - ar) * xsh8[i]);
    }
    *reinterpret_cast<bf16x8*>(&xk[g]) = ok_;
    *reinterpret_cast<bf16x8*>(&xv[g]) = ov_;
    *reinterpret_cast<bf16x8*>(&xr[g]) = or_;
}

// ---------------------------------------------------------------------------
// DEDICATED grouped-3x3 conv: 9-tap staged, c0-outer (8 barrier pairs vs 24).
// o-tile 64 x p-tile 128 (2 h rows); input/output TRANSPOSED [b][p][512].
// Alds [9][64][36] + Blds [4 rows][66][36] = 60.5 KB -> 2 blocks/CU.
// FIX r23: halo zeroing covers 288 slots via strided loop (256 threads).
// ---------------------------------------------------------------------------
__global__ __launch_bounds__(256, 2)
void conv9_kernel(const bf16_t* __restrict__ Wp, const bf16_t* __restrict__ XinT,
                  const float* __restrict__ bias, const float* __restrict__ bng,
                  const float* __restrict__ bnb, bf16_t* __restrict__ OutT)
{
    __shared__ bf16_t Alds[9 * 64 * 36];
    __shared__ bf16_t Blds[4 * 66 * 36];
    int tid = threadIdx.x;
    int bx = blockIdx.x;
    int o0 = blockIdx.y * 64;
    int b  = blockIdx.z;
    int p0 = bx << 7;
    int cbase = (o0 >> 8) << 8;

    int lane = tid & 63, wid = tid >> 6;
    int l15 = lane & 15;
    int lk8 = (lane >> 4) << 3;
    int mbase = (wid >> 1) << 5;    // 0 / 32
    int nbase = (wid & 1) << 6;     // 0 / 64

    const bf16_t* Xb = XinT + (size_t)b * 4096 * 512;

    f32x4 acc[2][4] = {};

    // zero halo columns (w 0 and 65) of all 4 rows: 4*2*36 = 288 slots
    for (int f = tid; f < 288; f += 256) {
        int rr = f / 72, rest = f % 72;
        int col = rest / 36, cc = rest % 36;
        Blds[(rr * 66 + (col ? 65 : 0)) * 36 + cc] = (bf16_t)0.f;
    }

    int wpos = tid >> 2, ch4 = tid & 3;
    int ao = tid >> 2, aq = tid & 3;

    for (int c0 = 0; c0 < 256; c0 += 32) {
        __syncthreads();
        // ---- stage B: 4 input rows (2bx-1 .. 2bx+2), transposed source ----
        #pragma unroll
        for (int rr = 0; rr < 4; ++rr) {
            int hr = (bx << 1) + rr - 1;
            bf16x8 bv;
            #pragma unroll
            for (int i = 0; i < 8; ++i) bv[i] = (bf16_t)0.f;
            if (hr >= 0 && hr < 64)
                bv = *reinterpret_cast<const bf16x8*>(
                       Xb + (size_t)((hr << 6) + wpos) * 512 + cbase + c0 + ch4 * 8);
            *reinterpret_cast<bf16x8*>(&Blds[(rr * 66 + wpos + 1) * 36 + ch4 * 8]) = bv;
        }
        // ---- stage A: all 9 taps x 64 rows x 32 c ----
        #pragma unroll
        for (int t = 0; t < 9; ++t) {
            bf16x8 wv = *reinterpret_cast<const bf16x8*>(
                Wp + ((size_t)t * 512 + o0 + ao) * 256 + c0 + aq * 8);
            *reinterpret_cast<bf16x8*>(&Alds[(t * 64 + ao) * 36 + aq * 8]) = wv;
        }
        __syncthreads();
        // ---- MFMA: 9 taps x 2 x 4 = 72 per stage ----
        #pragma unroll
        for (int kh = 0; kh < 3; ++kh) {
            #pragma unroll
            for (int kw = 0; kw < 3; ++kw) {
                int t = kh * 3 + kw;
                bf16x8 af[2];
                #pragma unroll
                for (int i = 0; i < 2; ++i)
                    af[i] = *reinterpret_cast<const bf16x8*>(
                              &Alds[(t * 64 + mbase + i * 16 + l15) * 36 + lk8]);
                #pragma unroll
                for (int j = 0; j < 4; ++j) {
                    int pl = nbase + j * 16;
                    int baddr = (((pl >> 6) + kh) * 66 + (pl & 63) + l15 + kw) * 36 + lk8;
                    bf16x8 bfv = *reinterpret_cast<const bf16x8*>(&Blds[baddr]);
                    #pragma unroll
                    for (int i = 0; i < 2; ++i)
                        acc[i][j] = __builtin_amdgcn_mfma_f32_16x16x32_bf16(
                                        af[i], bfv, acc[i][j], 0, 0, 0);
                }
            }
        }
    }

    const float bnsc = 1.0f / sqrtf(1.f + 1e-5f);
    #pragma unroll
    for (int i = 0; i < 2; ++i) {
        int ob = o0 + mbase + i * 16 + ((lane >> 4) << 2);
        float bi4[4], sc4[4], sh4[4];
        #pragma unroll
        for (int r = 0; r < 4; ++r) {
            bi4[r] = bias[ob + r];
            sc4[r] = bng[ob + r] * bnsc;
            sh4[r] = bnb[ob + r];
        }
        #pragma unroll
        for (int j = 0; j < 4; ++j) {
            int pp = p0 + nbase + j * 16 + l15;
            bf16x4 pk;
            #pragma unroll
            for (int r = 0; r < 4; ++r) {
                float t = acc[i][j][r] + bi4[r];
                t = 0.5f * t * (1.f + erff(t * 0.70710678118654752f));
                pk[r] = (bf16_t)(t * sc4[r] + sh4[r]);
            }
            *reinterpret_cast<bf16x4*>(
                &OutT[((size_t)b * 4096 + pp) * 512 + ob]) = pk;
        }
    }
}

// ---------------------------------------------------------------------------
// TILE x TILE bf16 MFMA 1x1 GEMM (r16/r18-proven structure).
// ---------------------------------------------------------------------------
#define EP_NONE    0
#define EP_SIGMOID 1
#define EP_BIAS    2
#define EP_RESLN   3
#define EP_GELU_BN 4
#define EP_SHUFFLE 5
#define EP_KVR     6
#define EP_WOSKIP  7

template<int NB, int BMODE, int EPI, int OUTBF, int TILE, int OTR>
__global__ __launch_bounds__(256, (TILE == 64) ? 4 : 2)
void mfma_gemm(const bf16_t* __restrict__ Wp, const void* __restrict__ Xin,
               const bf16_t* __restrict__ X2,
               const float2* __restrict__ bstats, const float* __restrict__ blnw,
               const float* __restrict__ blnb,
               const float* __restrict__ bias, const bf16_t* __restrict__ skipT,
               const float* __restrict__ bng, const float* __restrict__ bnb,
               const float* __restrict__ resx, const float2* __restrict__ estats,
               const float* __restrict__ elnw, const float* __restrict__ elnb,
               void* __restrict__ OutV,
               int O, int K, int Cstride, int obs, int ocoff)
{
    constexpr int MI = TILE / 32;
    constexpr int BROWS = TILE;
    __shared__ bf16_t Alds[NB * TILE * 36];
    __shared__ bf16_t Blds[BROWS * 36];
    int tid = threadIdx.x;
    int bx = blockIdx.x;
    int o0 = blockIdx.y * TILE;
    int b  = blockIdx.z;
    int p0 = bx * TILE;

    bool wo = true;
    int bb = b;
    if (EPI == EP_WOSKIP) { wo = (b >> 3) != 0; bb = b & 7; }

    const bf16_t* Wpe = Wp;
    if (EPI == EP_KVR)    Wpe = Wp + (size_t)(b >> 3) * O * K;
    if (EPI == EP_WOSKIP) Wpe = wo ? Wp : (Wp + 65536);
    int Krun = K;
    if (EPI == EP_WOSKIP) Krun = wo ? 256 : 512;

    int lane = tid & 63, wid = tid >> 6;
    int l15 = lane & 15;
    int lk8 = (lane >> 4) << 3;
    int mbase = (wid >> 1) * (TILE / 2);
    int nbase = (wid & 1) * (TILE / 2);

    const bf16_t* Xb_bf = (const bf16_t*)Xin + (size_t)bb * Cstride * 4096;
    const float*  Xb_f  = (const float*)Xin + (size_t)bb * Cstride * 4096;
    const bf16_t* X2b   = (BMODE == 3) ? X2 + (size_t)bb * Cstride * 4096 : nullptr;
    const bf16_t* skb   = (EPI == EP_WOSKIP)
                          ? skipT + (size_t)bb * 4096 * 512 : nullptr;

    f32x4 acc[MI][MI] = {};

    for (int c0 = 0; c0 < Krun; c0 += 32) {
        __syncthreads();
        // ---- stage B ----
        if (BMODE >= 4) {
            constexpr int NCH = (TILE == 128) ? 2 : 1;
            #pragma unroll
            for (int q = 0; q < NCH; ++q) {
                int cid = tid + q * 256;
                int p   = cid >> 2;
                int ch4 = cid & 3;
                bf16x8 bv = *reinterpret_cast<const bf16x8*>(
                    Xb_bf + (size_t)(p0 + p) * Cstride + c0 + ch4 * 8);
                if (BMODE == 5) {
                    float2 st = bstats[(bb << 12) + p0 + p];
                    #pragma unroll
                    for (int j = 0; j < 8; ++j) {
                        int cc = c0 + ch4 * 8 + j;
                        bv[j] = (bf16_t)(((float)bv[j] - st.x) * st.y
                                         * blnw[cc] + blnb[cc]);
                    }
                }
                *reinterpret_cast<bf16x8*>(&Blds[p * 36 + ch4 * 8]) = bv;
            }
        } else if (EPI == EP_WOSKIP) {
            int p = tid >> 2, ch4 = tid & 3;
            if (!wo) {
                bf16x8 bv = *reinterpret_cast<const bf16x8*>(
                    skb + (size_t)(p0 + p) * 512 + c0 + ch4 * 8);
                *reinterpret_cast<bf16x8*>(&Blds[p * 36 + ch4 * 8]) = bv;
            } else {
                bf16x8 wv = *reinterpret_cast<const bf16x8*>(
                    Xb_bf + (size_t)(p0 + p) * 256 + c0 + ch4 * 8);
                bf16x8 rv = *reinterpret_cast<const bf16x8*>(
                    X2b + (size_t)(p0 + p) * 256 + c0 + ch4 * 8);
                float2 st = bstats[(bb << 12) + p0 + p];
                bf16x8 bv;
                #pragma unroll
                for (int j = 0; j < 8; ++j) {
                    int cc = c0 + ch4 * 8 + j;
                    float v = ((float)wv[j] - st.x) * st.y * blnw[cc] + blnb[cc];
                    v *= (float)rv[j];
                    bv[j] = (bf16_t)v;
                }
                *reinterpret_cast<bf16x8*>(&Blds[p * 36 + ch4 * 8]) = bv;
            }
        } else {
            int p_loc = tid & (TILE - 1);
            #pragma unroll
            for (int rep = 0; rep < (TILE == 128 ? 2 : 1); ++rep) {
                int cgr = (TILE == 128) ? ((tid >> 7) + rep * 2) : (tid >> 6);
                bf16x8 bv;
                size_t gbase = (size_t)(c0 + cgr * 8) * 4096 + p0 + p_loc;
                #pragma unroll
                for (int j = 0; j < 8; ++j) {
                    size_t gi = gbase + (size_t)j * 4096;
                    if (BMODE == 0) bv[j] = Xb_bf[gi];
                    else            bv[j] = (bf16_t)Xb_f[gi];
                }
                *reinterpret_cast<bf16x8*>(&Blds[p_loc * 36 + cgr * 8]) = bv;
            }
        }
        // ---- stage A ----
        if (TILE == 128) {
            int ao = tid >> 1, aq = tid & 1;
            const bf16_t* wsrc = Wpe + (size_t)(o0 + ao) * Krun + c0;
            bf16x8 w0 = *reinterpret_cast<const bf16x8*>(wsrc + aq * 8);
            bf16x8 w1 = *reinterpret_cast<const bf16x8*>(wsrc + (aq + 2) * 8);
            *reinterpret_cast<bf16x8*>(&Alds[ao * 36 + aq * 8]) = w0;
            *reinterpret_cast<bf16x8*>(&Alds[ao * 36 + (aq + 2) * 8]) = w1;
        } else {
            int ao = tid >> 2, aq = tid & 3;
            const bf16_t* wsrc = Wpe + (size_t)(o0 + ao) * Krun + c0;
            bf16x8 w0 = *reinterpret_cast<const bf16x8*>(wsrc + aq * 8);
            *reinterpret_cast<bf16x8*>(&Alds[ao * 36 + aq * 8]) = w0;
        }
        __syncthreads();
        // ---- MFMA ----
        bf16x8 af[MI];
        #pragma unroll
        for (int i = 0; i < MI; ++i)
            af[i] = *reinterpret_cast<const bf16x8*>(
                      &Alds[(mbase + i * 16 + l15) * 36 + lk8]);
        #pragma unroll
        for (int j = 0; j < MI; ++j) {
            int pl = nbase + j * 16;
            bf16x8 bfv = *reinterpret_cast<const bf16x8*>(
                &Blds[(pl + l15) * 36 + lk8]);
            #pragma unroll
            for (int i = 0; i < MI; ++i)
                acc[i][j] = __builtin_amdgcn_mfma_f32_16x16x32_bf16(
                                af[i], bfv, acc[i][j], 0, 0, 0);
        }
    }

    const float bnsc = 1.0f / sqrtf(1.f + 1e-5f);

    if (EPI == EP_KVR && b >= 16) {
        bf16_t* rT = (bf16_t*)OutV + (size_t)16 * 256 * 4096;
        #pragma unroll
        for (int i = 0; i < MI; ++i) {
            int ob = o0 + mbase + i * 16 + ((lane >> 4) << 2);
            #pragma unroll
            for (int j = 0; j < MI; ++j) {
                int pp = p0 + nbase + j * 16 + l15;
                bf16x4 pk;
                #pragma unroll
                for (int r = 0; r < 4; ++r) {
                    float t = acc[i][j][r];
                    pk[r] = (bf16_t)(1.f / (1.f + expf(-t)));
                }
                *reinterpret_cast<bf16x4*>(
                    &rT[((size_t)(b - 16) * 4096 + pp) * 256 + ob]) = pk;
            }
        }
        return;
    }

    if (EPI == EP_WOSKIP) {
        int oco = wo ? 0 : 256;
        #pragma unroll
        for (int i = 0; i < MI; ++i) {
            int ob = o0 + mbase + i * 16 + ((lane >> 4) << 2);
            float bi4[4], rw4[4], rb4[4];
            #pragma unroll
            for (int r = 0; r < 4; ++r) {
                bi4[r] = wo ? 0.f : bias[ob + r];
                rw4[r] = wo ? elnw[ob + r] : 0.f;
                rb4[r] = wo ? elnb[ob + r] : 0.f;
            }
            #pragma unroll
            for (int j = 0; j < MI; ++j) {
                int pp = p0 + nbase + j * 16 + l15;
                float2 st = make_float2(0.f, 1.f);
                if (wo) st = estats[(bb << 12) + pp];
                bf16x4 pk;
                #pragma unroll
                for (int r = 0; r < 4; ++r) {
                    float t = acc[i][j][r];
                    if (!wo) {
                        t += bi4[r];
                    } else {
                        float rv = resx[((size_t)bb * 256 + ob + r) * 4096 + pp];
                        t += (rv - st.x) * st.y * rw4[r] + rb4[r];
                    }
                    pk[r] = (bf16_t)t;
                }
                *reinterpret_cast<bf16x4*>(
                    &((bf16_t*)OutV)[((size_t)bb * 4096 + pp) * 512 + oco + ob]) = pk;
            }
        }
        return;
    }

    if (EPI == EP_GELU_BN && OTR) {
        #pragma unroll
        for (int i = 0; i < MI; ++i) {
            int ob = o0 + mbase + i * 16 + ((lane >> 4) << 2);
            float bi4[4], sc4[4], sh4[4];
            #pragma unroll
            for (int r = 0; r < 4; ++r) {
                bi4[r] = bias[ob + r];
                sc4[r] = bng[ob + r] * bnsc;
                sh4[r] = bnb[ob + r];
            }
            #pragma unroll
            for (int j = 0; j < MI; ++j) {
                int pp = p0 + nbase + j * 16 + l15;
                bf16x4 pk;
                #pragma unroll
                for (int r = 0; r < 4; ++r) {
                    float t = acc[i][j][r] + bi4[r];
                    t = 0.5f * t * (1.f + erff(t * 0.70710678118654752f));
                    pk[r] = (bf16_t)(t * sc4[r] + sh4[r]);
                }
                *reinterpret_cast<bf16x4*>(
                    &((bf16_t*)OutV)[((size_t)bb * 4096 + pp) * obs + ocoff + ob]) = pk;
            }
        }
        return;
    }

    #pragma unroll
    for (int i = 0; i < MI; ++i) {
        #pragma unroll
        for (int r = 0; r < 4; ++r) {
            int o = o0 + mbase + i * 16 + ((lane >> 4) << 2) + r;
            float bi = 0.f;
            if (EPI == EP_BIAS || EPI == EP_GELU_BN || EPI == EP_SHUFFLE) bi = bias[o];
            float sc = 0.f, sh = 0.f;
            if (EPI == EP_GELU_BN) { sc = bng[o] * bnsc; sh = bnb[o]; }
            #pragma unroll
            for (int j = 0; j < MI; ++j) {
                int pp = p0 + nbase + j * 16 + l15;
                float t = acc[i][j][r];
                if (EPI == EP_SIGMOID) t = 1.f / (1.f + expf(-t));
                if (EPI == EP_BIAS || EPI == EP_GELU_BN || EPI == EP_SHUFFLE) t += bi;
                if (EPI == EP_GELU_BN) {
                    t = 0.5f * t * (1.f + erff(t * 0.70710678118654752f));
                    t = t * sc + sh;
                }
                if (EPI == EP_SHUFFLE) {
                    int co = o >> 2, s1 = (o >> 1) & 1, s2 = o & 1;
                    int hh = pp >> 6, ww = pp & 63;
                    ((float*)OutV)[(((size_t)bb * 128 + co) * 128 + hh * 2 + s1) * 128
                                   + ww * 2 + s2] = t;
                } else {
                    size_t oidx = ((size_t)bb * obs + ocoff + o) * 4096 + pp;
                    if (OUTBF) ((bf16_t*)OutV)[oidx] = (bf16_t)t;
                    else       ((float*)OutV)[oidx]  = t;
                }
            }
        }
    }
}

// ---------------------------------------------------------------------------
// Merged weight packing
// ---------------------------------------------------------------------------
__global__ __launch_bounds__(256)
void pack_all_kernel(const float* __restrict__ wk, const float* __restrict__ wv,
                     const float* __restrict__ wr, const float* __restrict__ wo,
                     const float* __restrict__ sp, const float* __restrict__ c2,
                     const float* __restrict__ c3, const float* __restrict__ up,
                     const float* __restrict__ c1, bf16_t* __restrict__ outfl,
                     bf16_t* __restrict__ outc1)
{
    int g = blockIdx.x * 256 + threadIdx.x;
    if (g < 1310720) {
        float v;
        if      (g < 65536)   v = wk[g];
        else if (g < 131072)  v = wv[g - 65536];
        else if (g < 196608)  v = wr[g - 131072];
        else if (g < 262144)  v = wo[g - 196608];
        else if (g < 393216)  v = sp[g - 262144];
        else if (g < 917504)  v = c2[g - 393216];
        else if (g < 1179648) v = c3[g - 917504];
        else                  v = up[g - 1179648];
        outfl[g] = (bf16_t)v;
    } else {
        int g2 = g - 1310720;
        if (g2 < 1179648) {
            int c = g2 & 255;
            int o = (g2 >> 8) & 511;
            int tap = g2 >> 17;
            outc1[g2] = (bf16_t)c1[(size_t)o * 2304 + c * 9 + tap];
        }
    }
}

// ---------------------------------------------------------------------------
// MERGED WKV scan: one block per (b,c) plane (64 threads).
// ---------------------------------------------------------------------------
__global__ __launch_bounds__(64)
void wkv_merged_kernel(const bf16_t* __restrict__ kin, const bf16_t* __restrict__ vin,
                       bf16_t* __restrict__ outw,
                       const float* __restrict__ decay, const float* __restrict__ first)
{
    __shared__ bf16_t ks[64 * 66];
    __shared__ bf16_t vs[64 * 66];
    __shared__ bf16_t os[64 * 66];
    int c = blockIdx.x;
    int b = blockIdx.y;
    int tid = threadIdx.x;
    size_t base = ((size_t)b * 256 + c) * 4096;

    uint32_t* ksu = (uint32_t*)ks;
    uint32_t* vsu = (uint32_t*)vs;
    uint32_t* osu = (uint32_t*)os;
    #pragma unroll
    for (int i = 0; i < 8; ++i) {
        int idx = i * 512 + tid * 8;
        int row = idx >> 6, col = idx & 63;
        bf16x8 kv = *reinterpret_cast<const bf16x8*>(&kin[base + idx]);
        bf16x8 vv = *reinterpret_cast<const bf16x8*>(&vin[base + idx]);
        uint32_t* kp = (uint32_t*)&kv;
        uint32_t* vp = (uint32_t*)&vv;
        #pragma unroll
        for (int q = 0; q < 4; ++q) {
            ksu[row * 33 + (col >> 1) + q] = kp[q];
            vsu[row * 33 + (col >> 1) + q] = vp[q];
        }
    }
    __syncthreads();

    float u  = first[c];
    float wn = -expf(decay[c]);

    {
        int h = tid;
        float a = 0.f, bb2 = 0.f, pp = -1e38f;
        for (int w = 0; w < 64; ++w) {
            float kt = (float)ks[h * 66 + w], vt = (float)vs[h * 66 + w];
            float q  = fmaxf(pp, u + kt);
            float e1 = expf(pp - q), e2 = expf(u + kt - q);
            float ov = (e1 * a + e2 * vt) / (e1 * bb2 + e2);
            os[h * 66 + w] = (bf16_t)ov;
            float q2 = fmaxf(pp + wn, kt);
            float f1 = expf(pp + wn - q2), f2 = expf(kt - q2);
            a = f1 * a + f2 * vt;
            bb2 = f1 * bb2 + f2;
            pp = q2;
        }
    }
    __syncthreads();

    {
        int w = tid;
        float a = 0.f, bb2 = 0.f, pp = -1e38f;
        for (int h = 0; h < 64; ++h) {
            float kt = (float)ks[h * 66 + w], vt = (float)vs[h * 66 + w];
            float q  = fmaxf(pp, u + kt);
            float e1 = expf(pp - q), e2 = expf(u + kt - q);
            float ov = (e1 * a + e2 * vt) / (e1 * bb2 + e2);
            os[h * 66 + w] = (bf16_t)(0.5f * ((float)os[h * 66 + w] + ov));
            float q2 = fmaxf(pp + wn, kt);
            float f1 = expf(pp + wn - q2), f2 = expf(kt - q2);
            a = f1 * a + f2 * vt;
            bb2 = f1 * bb2 + f2;
            pp = q2;
        }
    }
    __syncthreads();

    #pragma unroll
    for (int i = 0; i < 8; ++i) {
        int idx = i * 512 + tid * 8;
        int row = idx >> 6, col = idx & 63;
        bf16x8 ov;
        uint32_t* op = (uint32_t*)&ov;
        #pragma unroll
        for (int q = 0; q < 4; ++q)
            op[q] = osu[row * 33 + (col >> 1) + q];
        *reinterpret_cast<bf16x8*>(&outw[base + idx]) = ov;
    }
}

// ---------------------------------------------------------------------------
extern "C" void kernel_launch(void* const* d_in, const int* in_sizes, int n_in,
                              void* d_out, int out_size, void* d_ws, size_t ws_size,
                              hipStream_t stream)
{
    const float* x      = (const float*)d_in[0];
    const float* skip   = (const float*)d_in[1];
    const float* mask   = (const float*)d_in[2];
    const float* ln1_w  = (const float*)d_in[3];
    const float* ln1_b  = (const float*)d_in[4];
    const float* ln2_w  = (const float*)d_in[5];
    const float* ln2_b  = (const float*)d_in[6];
    const float* mix_k  = (const float*)d_in[7];
    const float* mix_v  = (const float*)d_in[8];
    const float* mix_r  = (const float*)d_in[9];
    const float* Wk     = (const float*)d_in[10];
    const float* Wv     = (const float*)d_in[11];
    const float* Wr     = (const float*)d_in[12];
    const float* Wo     = (const float*)d_in[13];
    const float* decay  = (const float*)d_in[14];
    const float* first  = (const float*)d_in[15];
    const float* kn_w   = (const float*)d_in[16];
    const float* kn_b   = (const float*)d_in[17];
    const float* sp_w   = (const float*)d_in[18];
    const float* sp_b   = (const float*)d_in[19];
    const float* c1_w   = (const float*)d_in[20];
    const float* c1_b   = (const float*)d_in[21];
    const float* bn1_g  = (const float*)d_in[22];
    const float* bn1_b  = (const float*)d_in[23];
    const float* c2_w   = (const float*)d_in[24];
    const float* c2_b   = (const float*)d_in[25];
    const float* bn2_g  = (const float*)d_in[26];
    const float* bn2_b  = (const float*)d_in[27];
    const float* c3_w   = (const float*)d_in[28];
    const float* c3_b   = (const float*)d_in[29];
    const float* bn3_g  = (const float*)d_in[30];
    const float* bn3_b  = (const float*)d_in[31];
    const float* up_w   = (const float*)d_in[32];
    const float* up_b   = (const float*)d_in[33];
    float* out = (float*)d_out;

    float* ws = (float*)d_ws;
    const size_t S = 8388608;
    const size_t Hs = S / 2;
    bf16_t* xk   = (bf16_t*)ws;
    bf16_t* xv   = (bf16_t*)(ws + Hs);
    bf16_t* xr   = (bf16_t*)(ws + 2 * Hs);
    bf16_t* wkvT = (bf16_t*)(ws + 2 * Hs);          // TRANSPOSED wkv [b][p][256]
    bf16_t* kbuf = (bf16_t*)(ws + 3 * Hs);
    bf16_t* vbuf = (bf16_t*)(ws + 4 * Hs);
    bf16_t* rbuf = (bf16_t*)(ws + 5 * Hs);          // TRANSPOSED rbufT
    bf16_t* wkv  = (bf16_t*)(ws + 6 * Hs);
    bf16_t* xcat = (bf16_t*)(ws + 7 * Hs);          // TRANSPOSED [b][p][512]
    bf16_t* skbf = (bf16_t*)(ws + 9 * Hs);          // TRANSPOSED bf16 skip
    bf16_t* y1   = (bf16_t*)(ws + 9 * Hs);          // reuses skbf
    bf16_t* y2   = (bf16_t*)ws;                     // TRANSPOSED [b][p][1024]
    bf16_t* y3   = (bf16_t*)(ws + 4 * Hs);          // TRANSPOSED [b][p][256]
    float*  wtop = ws + 11 * Hs;
    bf16_t* w9   = (bf16_t*)wtop;
    bf16_t* wfl  = w9 + 1179648;
    float2* st1  = (float2*)(wfl + 1310720);
    float2* stk  = st1 + 32768;
    float2* st2  = stk + 32768;
    bf16_t* wkb = wfl;
    bf16_t* wob = wfl + 196608;
    bf16_t* c2b = wfl + 393216;
    bf16_t* c3b = wfl + 917504;
    bf16_t* upb = wfl + 1179648;

    dim3 blk(256);

    pack_all_kernel<<<dim3(9728), blk, 0, stream>>>(Wk, Wv, Wr, Wo, sp_w, c2_w,
                                                    c3_w, up_w, c1_w, wfl, w9);
    ln_stats_kernel<float, 0, 0><<<dim3(512), blk, 0, stream>>>(x, st1, nullptr);
    skip_transpose_kernel<<<dim3(64, 8, 8), blk, 0, stream>>>(skip, skbf);

    qshift_mix_kernel<<<dim3(4096), blk, 0, stream>>>(x, st1, mask, ln1_w, ln1_b,
                                                      mix_k, mix_v, mix_r, xk, xv, xr);
    // k, v, sr in ONE launch (r -> sigmoid + transposed rbufT)
    mfma_gemm<1, 0, EP_KVR, 1, 64, 0><<<dim3(64, 4, 24), blk, 0, stream>>>(
        wkb, xk, nullptr, nullptr, nullptr, nullptr, nullptr, nullptr, nullptr,
        nullptr, nullptr, nullptr, nullptr, nullptr, kbuf, 256, 256, 256, 256, 0);
    // merged WKV scan
    wkv_merged_kernel<<<dim3(256, 8), dim3(64), 0, stream>>>(kbuf, vbuf, wkv, decay, first);
    // kn-LN stats + transposed wkv copy
    ln_stats_kernel<bf16_t, 0, 1><<<dim3(512), blk, 0, stream>>>(wkv, stk, wkvT);
    // MERGED woskip -> TRANSPOSED xcat
    mfma_gemm<1, 3, EP_WOSKIP, 1, 64, 0><<<dim3(64, 4, 16), blk, 0, stream>>>(
        wob, wkvT, rbuf, stk, kn_w, kn_b, sp_b, skbf, nullptr, nullptr,
        x, st1, ln1_w, ln1_b, xcat, 256, 0, 256, 512, 0);
    // DEDICATED 9-tap conv (8 barrier pairs, 72 MFMA/stage) -> TRANSPOSED y1
    conv9_kernel<<<dim3(32, 8, 8), blk, 0, stream>>>(w9, xcat, c1_b, bn1_g, bn1_b, y1);
    // c2 (transposed in) -> TRANSPOSED y2
    mfma_gemm<1, 4, EP_GELU_BN, 1, 128, 1><<<dim3(32, 8, 8), blk, 0, stream>>>(
        c2b, y1, nullptr, nullptr, nullptr, nullptr, c2_b, nullptr, bn2_g, bn2_b,
        nullptr, nullptr, nullptr, nullptr, y2, 1024, 512, 512, 1024, 0);
    // c3 (transposed in) -> TRANSPOSED y3
    mfma_gemm<1, 4, EP_GELU_BN, 1, 64, 1><<<dim3(64, 4, 8), blk, 0, stream>>>(
        c3b, y2, nullptr, nullptr, nullptr, nullptr, c3_b, nullptr, bn3_g, bn3_b,
        nullptr, nullptr, nullptr, nullptr, y3, 256, 1024, 1024, 256, 0);
    ln_stats_kernel<bf16_t, 1, 0><<<dim3(512), blk, 0, stream>>>(y3, st2, nullptr);
    // up-projection (transposed in + LN2 folded) + pixel shuffle -> out
    mfma_gemm<1, 5, EP_SHUFFLE, 0, 64, 0><<<dim3(64, 8, 8), blk, 0, stream>>>(
        upb, y3, nullptr, st2, ln2_w, ln2_b, up_b, nullptr, nullptr, nullptr,
        nullptr, nullptr, nullptr, nullptr, out, 512, 256, 256, 0, 0);
}

// Round 26
// 467.934 us; speedup vs baseline: 1.0648x; 1.0648x over previous
//
#include <hip/hip_runtime.h>
#include <hip/hip_bf16.h>
#include <math.h>

#define B_ 8
#define C_ 256
#define P_ 4096

typedef __bf16 bf16_t;
typedef __attribute__((ext_vector_type(8))) __bf16 bf16x8;
typedef __attribute__((ext_vector_type(4))) __bf16 bf16x4;
typedef __attribute__((ext_vector_type(4))) float f32x4;

// ---------------------------------------------------------------------------
// Channel-LN stats. TRANS=0: in[b][c][p]; TRANS=1: in[b][p][C] bf16 rows.
// ---------------------------------------------------------------------------
template<typename T, int TRANS>
__global__ __launch_bounds__(256)
void ln_stats_kernel(const T* __restrict__ in, float2* __restrict__ stats)
{
    __shared__ float sred[4][64];
    __shared__ float s2red[4][64];
    int tid = threadIdx.x;
    if (TRANS) {
        int wp = tid >> 2, cw = tid & 3;
        int gp = blockIdx.x * 64 + wp;
        const bf16_t* row = (const bf16_t*)in + (size_t)gp * 256 + cw * 64;
        float s = 0.f, s2 = 0.f;
        #pragma unroll
        for (int i = 0; i < 64; i += 8) {
            bf16x8 v = *reinterpret_cast<const bf16x8*>(&row[i]);
            #pragma unroll
            for (int j = 0; j < 8; ++j) {
                float f = (float)v[j]; s += f; s2 += f * f;
            }
        }
        sred[cw][wp] = s; s2red[cw][wp] = s2;
        __syncthreads();
        if (cw == 0) {
            s  = sred[0][wp]  + sred[1][wp]  + sred[2][wp]  + sred[3][wp];
            s2 = s2red[0][wp] + s2red[1][wp] + s2red[2][wp] + s2red[3][wp];
            float mu  = s * (1.f / 256.f);
            float var = s2 * (1.f / 256.f) - mu * mu;
            stats[gp] = make_float2(mu, 1.0f / sqrtf(var + 1e-5f));
        }
        return;
    }
    int wp = tid & 63, cw = tid >> 6;
    int gp = blockIdx.x * 64 + wp;
    int b  = gp >> 12, p = gp & 4095;
    size_t base = (size_t)b * 256 * 4096 + p;
    float s = 0.f, s2 = 0.f;
    #pragma unroll 8
    for (int cc = 0; cc < 64; ++cc) {
        float v = (float)in[base + (size_t)(cw * 64 + cc) * 4096];
        s += v; s2 += v * v;
    }
    sred[cw][wp] = s; s2red[cw][wp] = s2;
    __syncthreads();
    if (cw == 0) {
        s  = sred[0][wp]  + sred[1][wp]  + sred[2][wp]  + sred[3][wp];
        s2 = s2red[0][wp] + s2red[1][wp] + s2red[2][wp] + s2red[3][wp];
        float mu  = s * (1.f / 256.f);
        float var = s2 * (1.f / 256.f) - mu * mu;
        stats[gp] = make_float2(mu, 1.0f / sqrtf(var + 1e-5f));
    }
}

// ---------------------------------------------------------------------------
// skip transpose: f32 [b][512][4096] -> bf16 [b][p][512], LDS 64x64 tile.
// Bit-identical to converting inside the GEMM staging (same bf16 rounding).
// ---------------------------------------------------------------------------
__global__ __launch_bounds__(256)
void skip_transpose_kernel(const float* __restrict__ in, bf16_t* __restrict__ outT)
{
    __shared__ bf16_t t[64 * 66];
    int p0 = blockIdx.x << 6;
    int c0 = blockIdx.y << 6;
    int b  = blockIdx.z;
    int tid = threadIdx.x;
    int pl = tid & 63, cq = tid >> 6;
    const float* src = in + ((size_t)b * 512 + c0) * 4096 + p0;
    #pragma unroll
    for (int i = 0; i < 16; ++i) {
        int cl = i * 4 + cq;
        t[pl * 66 + cl] = (bf16_t)src[(size_t)cl * 4096 + pl];
    }
    __syncthreads();
    int pw = tid >> 2, ch = tid & 3;
    bf16x8 v0 = *reinterpret_cast<const bf16x8*>(&t[pw * 66 + ch * 16]);
    bf16x8 v1 = *reinterpret_cast<const bf16x8*>(&t[pw * 66 + ch * 16 + 8]);
    bf16_t* dst = outT + ((size_t)b * 4096 + p0 + pw) * 512 + c0 + ch * 16;
    *reinterpret_cast<bf16x8*>(dst) = v0;
    *reinterpret_cast<bf16x8*>(dst + 8) = v1;
}

// ---------------------------------------------------------------------------
// Fused LN1 + q_shift + blend + 3-way mix, vectorized x8 along w.
// ---------------------------------------------------------------------------
__global__ __launch_bounds__(256)
void qshift_mix_kernel(const float* __restrict__ x, const float2* __restrict__ st1,
                       const float* __restrict__ mask,
                       const float* __restrict__ gw, const float* __restrict__ gb,
                       const float* __restrict__ mk_, const float* __restrict__ mv_,
                       const float* __restrict__ mr_,
                       bf16_t* __restrict__ xk, bf16_t* __restrict__ xv,
                       bf16_t* __restrict__ xr)
{
    int gid = blockIdx.x * 256 + threadIdx.x;
    int g = gid << 3;
    int p = g & 4095;
    int c = (g >> 12) & 255;
    int b = g >> 20;
    int h = p >> 6, w0 = p & 63;
    float gwc = gw[c], gbc = gb[c];
    int sbase = (b << 12) + p;

    float4 x0 = *reinterpret_cast<const float4*>(&x[g]);
    float4 x1 = *reinterpret_cast<const float4*>(&x[g + 4]);
    float xv8[8] = {x0.x, x0.y, x0.z, x0.w, x1.x, x1.y, x1.z, x1.w};
    float2 s8[8];
    #pragma unroll
    for (int i = 0; i < 4; ++i) {
        float4 t = *reinterpret_cast<const float4*>(&st1[sbase + i * 2]);
        s8[2 * i]     = make_float2(t.x, t.y);
        s8[2 * i + 1] = make_float2(t.z, t.w);
    }
    float xn8[8];
    #pragma unroll
    for (int i = 0; i < 8; ++i)
        xn8[i] = (xv8[i] - s8[i].x) * s8[i].y * gwc + gbc;

    float xs8[8];
    int quad = c >> 6;
    if (quad == 0) {
        xs8[0] = 0.f;
        if (w0 > 0) {
            float xm = x[g - 1]; float2 sm = st1[sbase - 1];
            xs8[0] = (xm - sm.x) * sm.y * gwc + gbc;
        }
        #pragma unroll
        for (int i = 1; i < 8; ++i) xs8[i] = xn8[i - 1];
    } else if (quad == 1) {
        #pragma unroll
        for (int i = 0; i < 7; ++i) xs8[i] = xn8[i + 1];
        xs8[7] = 0.f;
        if (w0 + 8 < 64) {
            float xp = x[g + 8]; float2 sp = st1[sbase + 8];
            xs8[7] = (xp - sp.x) * sp.y * gwc + gbc;
        }
    } else {
        int d = (quad == 2) ? -64 : 64;
        bool ok = (quad == 2) ? (h > 0) : (h < 63);
        if (ok) {
            float4 y0 = *reinterpret_cast<const float4*>(&x[g + d]);
            float4 y1 = *reinterpret_cast<const float4*>(&x[g + d + 4]);
            float yv8[8] = {y0.x, y0.y, y0.z, y0.w, y1.x, y1.y, y1.z, y1.w};
            #pragma unroll
            for (int i = 0; i < 4; ++i) {
                float4 t = *reinterpret_cast<const float4*>(&st1[sbase + d + i * 2]);
                float2 sa = make_float2(t.x, t.y), sb = make_float2(t.z, t.w);
                xs8[2 * i]     = (yv8[2 * i]     - sa.x) * sa.y * gwc + gbc;
                xs8[2 * i + 1] = (yv8[2 * i + 1] - sb.x) * sb.y * gwc + gbc;
            }
        } else {
            #pragma unroll
            for (int i = 0; i < 8; ++i) xs8[i] = 0.f;
        }
    }

    float4 m0 = *reinterpret_cast<const float4*>(&mask[sbase]);
    float4 m1 = *reinterpret_cast<const float4*>(&mask[sbase + 4]);
    float mm[8] = {m0.x, m0.y, m0.z, m0.w, m1.x, m1.y, m1.z, m1.w};
    float xsh8[8];
    #pragma unroll
    for (int i = 0; i < 8; ++i)
        xsh8[i] = mm[i] * xs8[i] + (1.f - mm[i]) * xn8[i];

    float ak = mk_[c], av = mv_[c], ar = mr_[c];
    bf16x8 ok_, ov_, or_;
    #pragma unroll
    for (int i = 0; i < 8; ++i) {
        ok_[i] = (bf16_t)(ak * xn8[i] + (1.f - ak) * xsh8[i]);
        ov_[i] = (bf16_t)(av * xn8[i] + (1.f - av) * xsh8[i]);
        or_[i] = (bf16_t)(ar * xn8[i] + (1.f - ar) * xsh8[i]);
    }
    *reinterpret_cast<bf16x8*>(&xk[g]) = ok_;
    *reinterpret_cast<bf16x8*>(&xv[g]) = ov_;
    *reinterpret_cast<bf16x8*>(&xr[g]) = or_;
}

// ---------------------------------------------------------------------------
// TILE x TILE bf16 MFMA implicit GEMM (r18 known-good: VGPR 64, BK=32,
// 2-barrier; conv NB=3 TILE=128 with transposed input).
//   woskip skip path reads TRANSPOSED bf16 skip [b][p][512] (16B chunks).
// ---------------------------------------------------------------------------
#define EP_NONE    0
#define EP_SIGMOID 1
#define EP_BIAS    2
#define EP_RESLN   3
#define EP_GELU_BN 4
#define EP_SHUFFLE 5
#define EP_KVR     6
#define EP_WOSKIP  7

template<int NB, int BMODE, int EPI, int OUTBF, int TILE, int OTR>
__global__ __launch_bounds__(256, (TILE == 64) ? 4 : 2)
void mfma_gemm(const bf16_t* __restrict__ Wp, const void* __restrict__ Xin,
               const bf16_t* __restrict__ X2,
               const float2* __restrict__ bstats, const float* __restrict__ blnw,
               const float* __restrict__ blnb,
               const float* __restrict__ bias, const bf16_t* __restrict__ skipT,
               const float* __restrict__ bng, const float* __restrict__ bnb,
               const float* __restrict__ resx, const float2* __restrict__ estats,
               const float* __restrict__ elnw, const float* __restrict__ elnb,
               void* __restrict__ OutV,
               int O, int K, int Cstride, int obs, int ocoff)
{
    constexpr int MI = TILE / 32;
    constexpr int BROWS = (NB == 3) ? 2 * 66 : TILE;
    __shared__ bf16_t Alds[NB * TILE * 36];
    __shared__ bf16_t Blds[BROWS * 36];
    int tid = threadIdx.x;
    int bx = blockIdx.x;
    int o0 = blockIdx.y * TILE;
    int b  = blockIdx.z;
    int p0 = bx * TILE;
    int cbase = (NB == 3) ? ((o0 >> 8) << 8) : 0;

    bool wo = true;
    int bb = b;
    if (EPI == EP_WOSKIP) { wo = (b >> 3) != 0; bb = b & 7; }

    const bf16_t* Wpe = Wp;
    if (EPI == EP_KVR)    Wpe = Wp + (size_t)(b >> 3) * O * K;
    if (EPI == EP_WOSKIP) Wpe = wo ? Wp : (Wp + 65536);
    int Krun = K;
    if (EPI == EP_WOSKIP) Krun = wo ? 256 : 512;

    int lane = tid & 63, wid = tid >> 6;
    int l15 = lane & 15;
    int lk8 = (lane >> 4) << 3;
    int mbase = (wid >> 1) * (TILE / 2);
    int nbase = (wid & 1) * (TILE / 2);

    const bf16_t* Xb_bf = (const bf16_t*)Xin + (size_t)bb * Cstride * 4096;
    const float*  Xb_f  = (const float*)Xin + (size_t)bb * Cstride * 4096;
    const bf16_t* X2b   = (BMODE == 3) ? X2 + (size_t)bb * Cstride * 4096 : nullptr;
    const bf16_t* skb   = (EPI == EP_WOSKIP)
                          ? skipT + (size_t)bb * 4096 * 512 : nullptr;

    f32x4 acc[MI][MI] = {};

    if (NB == 3 && tid < 144) {
        int r = tid / 72, rest = tid % 72;
        int col = rest / 36, cc = rest % 36;
        Blds[(r * 66 + (col ? 65 : 0)) * 36 + cc] = (bf16_t)0.f;
    }

    for (int kh = 0; kh < NB; ++kh) {
        for (int c0 = 0; c0 < Krun; c0 += 32) {
            __syncthreads();
            // ---- stage B ----
            if (NB == 3) {
                // transposed input [p][512]: 512 16B chunks, 2 per thread
                #pragma unroll
                for (int q = 0; q < 2; ++q) {
                    int cid = tid + q * 256;
                    int r   = cid >> 8;
                    int w   = (cid >> 2) & 63;
                    int ch4 = cid & 3;
                    int hr  = (bx << 1) + kh - 1 + r;
                    bf16x8 bv;
                    #pragma unroll
                    for (int i = 0; i < 8; ++i) bv[i] = (bf16_t)0.f;
                    if (hr >= 0 && hr < 64)
                        bv = *reinterpret_cast<const bf16x8*>(
                               Xb_bf + (size_t)((hr << 6) + w) * 512
                                     + cbase + c0 + ch4 * 8);
                    *reinterpret_cast<bf16x8*>(
                        &Blds[(r * 66 + w + 1) * 36 + ch4 * 8]) = bv;
                }
            } else if (BMODE >= 4) {
                constexpr int NCH = (TILE == 128) ? 2 : 1;
                #pragma unroll
                for (int q = 0; q < NCH; ++q) {
                    int cid = tid + q * 256;
                    int p   = cid >> 2;
                    int ch4 = cid & 3;
                    bf16x8 bv = *reinterpret_cast<const bf16x8*>(
                        Xb_bf + (size_t)(p0 + p) * Cstride + c0 + ch4 * 8);
                    if (BMODE == 5) {
                        float2 st = bstats[(bb << 12) + p0 + p];
                        #pragma unroll
                        for (int j = 0; j < 8; ++j) {
                            int cc = c0 + ch4 * 8 + j;
                            bv[j] = (bf16_t)(((float)bv[j] - st.x) * st.y
                                             * blnw[cc] + blnb[cc]);
                        }
                    }
                    *reinterpret_cast<bf16x8*>(&Blds[p * 36 + ch4 * 8]) = bv;
                }
            } else if (EPI == EP_WOSKIP && !wo) {
                // transposed bf16 skip [p][512]: one 16B chunk per thread
                int p = tid >> 2, ch4 = tid & 3;
                bf16x8 bv = *reinterpret_cast<const bf16x8*>(
                    skb + (size_t)(p0 + p) * 512 + c0 + ch4 * 8);
                *reinterpret_cast<bf16x8*>(&Blds[p * 36 + ch4 * 8]) = bv;
            } else {
                int p_loc = tid & (TILE - 1);
                float2 st = make_float2(0.f, 1.f);
                if (BMODE == 3)
                    st = bstats[(bb << 12) + p0 + p_loc];
                #pragma unroll
                for (int rep = 0; rep < (TILE == 128 ? 2 : 1); ++rep) {
                    int cgr = (TILE == 128) ? ((tid >> 7) + rep * 2) : (tid >> 6);
                    bf16x8 bv;
                    size_t gbase = (size_t)(c0 + cgr * 8) * 4096 + p0 + p_loc;
                    #pragma unroll
                    for (int j = 0; j < 8; ++j) {
                        size_t gi = gbase + (size_t)j * 4096;
                        int cc = c0 + cgr * 8 + j;
                        if (BMODE == 0) {
                            bv[j] = Xb_bf[gi];
                        } else {
                            float v = ((float)Xb_bf[gi] - st.x) * st.y * blnw[cc] + blnb[cc];
                            if (BMODE == 3) v *= (float)X2b[gi];
                            bv[j] = (bf16_t)v;
                        }
                    }
                    *reinterpret_cast<bf16x8*>(&Blds[p_loc * 36 + cgr * 8]) = bv;
                }
            }
            // ---- stage A ----
            if (TILE == 128) {
                int ao = tid >> 1, aq = tid & 1;
                #pragma unroll
                for (int t = 0; t < NB; ++t) {
                    const bf16_t* wsrc = (NB == 3)
                        ? Wpe + ((size_t)(kh * 3 + t) * O + o0 + ao) * 256 + c0
                        : Wpe + (size_t)(o0 + ao) * Krun + c0;
                    bf16x8 w0 = *reinterpret_cast<const bf16x8*>(wsrc + aq * 8);
                    bf16x8 w1 = *reinterpret_cast<const bf16x8*>(wsrc + (aq + 2) * 8);
                    *reinterpret_cast<bf16x8*>(&Alds[(t * 128 + ao) * 36 + aq * 8]) = w0;
                    *reinterpret_cast<bf16x8*>(&Alds[(t * 128 + ao) * 36 + (aq + 2) * 8]) = w1;
                }
            } else {
                int ao = tid >> 2, aq = tid & 3;
                const bf16_t* wsrc = Wpe + (size_t)(o0 + ao) * Krun + c0;
                bf16x8 w0 = *reinterpret_cast<const bf16x8*>(wsrc + aq * 8);
                *reinterpret_cast<bf16x8*>(&Alds[ao * 36 + aq * 8]) = w0;
            }
            __syncthreads();
            // ---- MFMA ----
            #pragma unroll
            for (int t = 0; t < NB; ++t) {
                bf16x8 af[MI];
                #pragma unroll
                for (int i = 0; i < MI; ++i)
                    af[i] = *reinterpret_cast<const bf16x8*>(
                              &Alds[(t * TILE + mbase + i * 16 + l15) * 36 + lk8]);
                #pragma unroll
                for (int j = 0; j < MI; ++j) {
                    int pl = nbase + j * 16;
                    int baddr;
                    if (NB == 3)
                        baddr = ((pl >> 6) * 66 + (pl & 63) + l15 + t) * 36 + lk8;
                    else
                        baddr = (pl + l15) * 36 + lk8;
                    bf16x8 bfv = *reinterpret_cast<const bf16x8*>(&Blds[baddr]);
                    #pragma unroll
                    for (int i = 0; i < MI; ++i)
                        acc[i][j] = __builtin_amdgcn_mfma_f32_16x16x32_bf16(
                                        af[i], bfv, acc[i][j], 0, 0, 0);
                }
            }
        }
    }

    const float bnsc = 1.0f / sqrtf(1.f + 1e-5f);
    bool kvr_sig = (EPI == EP_KVR) && (b >= 16);

    if (EPI == EP_WOSKIP) {
        int oco = wo ? 0 : 256;
        #pragma unroll
        for (int i = 0; i < MI; ++i) {
            int ob = o0 + mbase + i * 16 + ((lane >> 4) << 2);
            float bi4[4], rw4[4], rb4[4];
            #pragma unroll
            for (int r = 0; r < 4; ++r) {
                bi4[r] = wo ? 0.f : bias[ob + r];
                rw4[r] = wo ? elnw[ob + r] : 0.f;
                rb4[r] = wo ? elnb[ob + r] : 0.f;
            }
            #pragma unroll
            for (int j = 0; j < MI; ++j) {
                int pp = p0 + nbase + j * 16 + l15;
                float2 st = make_float2(0.f, 1.f);
                if (wo) st = estats[(bb << 12) + pp];
                bf16x4 pk;
                #pragma unroll
                for (int r = 0; r < 4; ++r) {
                    float t = acc[i][j][r];
                    if (!wo) {
                        t += bi4[r];
                    } else {
                        float rv = resx[((size_t)bb * 256 + ob + r) * 4096 + pp];
                        t += (rv - st.x) * st.y * rw4[r] + rb4[r];
                    }
                    pk[r] = (bf16_t)t;
                }
                *reinterpret_cast<bf16x4*>(
                    &((bf16_t*)OutV)[((size_t)bb * 4096 + pp) * 512 + oco + ob]) = pk;
            }
        }
        return;
    }

    if (EPI == EP_GELU_BN && OTR) {
        #pragma unroll
        for (int i = 0; i < MI; ++i) {
            int ob = o0 + mbase + i * 16 + ((lane >> 4) << 2);
            float bi4[4], sc4[4], sh4[4];
            #pragma unroll
            for (int r = 0; r < 4; ++r) {
                bi4[r] = bias[ob + r];
                sc4[r] = bng[ob + r] * bnsc;
                sh4[r] = bnb[ob + r];
            }
            #pragma unroll
            for (int j = 0; j < MI; ++j) {
                int pp = p0 + nbase + j * 16 + l15;
                bf16x4 pk;
                #pragma unroll
                for (int r = 0; r < 4; ++r) {
                    float t = acc[i][j][r] + bi4[r];
                    t = 0.5f * t * (1.f + erff(t * 0.70710678118654752f));
                    pk[r] = (bf16_t)(t * sc4[r] + sh4[r]);
                }
                *reinterpret_cast<bf16x4*>(
                    &((bf16_t*)OutV)[((size_t)bb * 4096 + pp) * obs + ocoff + ob]) = pk;
            }
        }
        return;
    }

    #pragma unroll
    for (int i = 0; i < MI; ++i) {
        #pragma unroll
        for (int r = 0; r < 4; ++r) {
            int o = o0 + mbase + i * 16 + ((lane >> 4) << 2) + r;
            float bi = 0.f;
            if (EPI == EP_BIAS || EPI == EP_GELU_BN || EPI == EP_SHUFFLE) bi = bias[o];
            float sc = 0.f, sh = 0.f;
            if (EPI == EP_GELU_BN) { sc = bng[o] * bnsc; sh = bnb[o]; }
            float rw = 0.f, rb = 0.f;
            if (EPI == EP_RESLN) { rw = elnw[o]; rb = elnb[o]; }
            #pragma unroll
            for (int j = 0; j < MI; ++j) {
                int pp = p0 + nbase + j * 16 + l15;
                float t = acc[i][j][r];
                if (EPI == EP_SIGMOID) t = 1.f / (1.f + expf(-t));
                if (EPI == EP_KVR && kvr_sig) t = 1.f / (1.f + expf(-t));
                if (EPI == EP_BIAS || EPI == EP_GELU_BN || EPI == EP_SHUFFLE) t += bi;
                if (EPI == EP_RESLN) {
                    float2 st = estats[(bb << 12) + pp];
                    float rv = resx[((size_t)bb * 256 + o) * 4096 + pp];
                    t += (rv - st.x) * st.y * rw + rb;
                }
                if (EPI == EP_GELU_BN) {
                    t = 0.5f * t * (1.f + erff(t * 0.70710678118654752f));
                    t = t * sc + sh;
                }
                if (EPI == EP_SHUFFLE) {
                    int co = o >> 2, s1 = (o >> 1) & 1, s2 = o & 1;
                    int hh = pp >> 6, ww = pp & 63;
                    ((float*)OutV)[(((size_t)bb * 128 + co) * 128 + hh * 2 + s1) * 128
                                   + ww * 2 + s2] = t;
                } else {
                    size_t oidx = ((size_t)bb * obs + ocoff + o) * 4096 + pp;
                    if (OUTBF) ((bf16_t*)OutV)[oidx] = (bf16_t)t;
                    else       ((float*)OutV)[oidx]  = t;
                }
            }
        }
    }
}

// ---------------------------------------------------------------------------
// Merged weight packing: flat 1x1 weights (1,310,720) + conv repack (1,179,648)
// ---------------------------------------------------------------------------
__global__ __launch_bounds__(256)
void pack_all_kernel(const float* __restrict__ wk, const float* __restrict__ wv,
                     const float* __restrict__ wr, const float* __restrict__ wo,
                     const float* __restrict__ sp, const float* __restrict__ c2,
                     const float* __restrict__ c3, const float* __restrict__ up,
                     const float* __restrict__ c1, bf16_t* __restrict__ outfl,
                     bf16_t* __restrict__ outc1)
{
    int g = blockIdx.x * 256 + threadIdx.x;
    if (g < 1310720) {
        float v;
        if      (g < 65536)   v = wk[g];
        else if (g < 131072)  v = wv[g - 65536];
        else if (g < 196608)  v = wr[g - 131072];
        else if (g < 262144)  v = wo[g - 196608];
        else if (g < 393216)  v = sp[g - 262144];
        else if (g < 917504)  v = c2[g - 393216];
        else if (g < 1179648) v = c3[g - 917504];
        else                  v = up[g - 1179648];
        outfl[g] = (bf16_t)v;
    } else {
        int g2 = g - 1310720;
        if (g2 < 1179648) {
            int c = g2 & 255;
            int o = (g2 >> 8) & 511;
            int tap = g2 >> 17;
            outc1[g2] = (bf16_t)c1[(size_t)o * 2304 + c * 9 + tap];
        }
    }
}

// ---------------------------------------------------------------------------
// WKV scans (bf16 I/O; bf16 LDS planes; f32 scan math)
// ---------------------------------------------------------------------------
__global__ __launch_bounds__(64)
void wkv_h_kernel(const bf16_t* __restrict__ kin, const bf16_t* __restrict__ vin,
                  bf16_t* __restrict__ outw,
                  const float* __restrict__ decay, const float* __restrict__ first)
{
    __shared__ bf16_t ks[64 * 66];
    __shared__ bf16_t vs[64 * 66];
    int c0 = blockIdx.x * 64;
    int h  = blockIdx.y;
    int b  = blockIdx.z;
    int tid = threadIdx.x;
    size_t base = (((size_t)b * 256 + c0) * 64 + h) * 64;

    for (int f = tid; f < 64 * 64; f += 64) {
        int cc = f >> 6, w = f & 63;
        ks[cc * 66 + w] = kin[base + (size_t)cc * 4096 + w];
        vs[cc * 66 + w] = vin[base + (size_t)cc * 4096 + w];
    }
    __syncthreads();

    int c = c0 + tid;
    float u  = first[c];
    float wn = -expf(decay[c]);
    float a = 0.f, bb = 0.f, pp = -1e38f;
    for (int t = 0; t < 64; ++t) {
        float kt = (float)ks[tid * 66 + t], vt = (float)vs[tid * 66 + t];
        float q  = fmaxf(pp, u + kt);
        float e1 = expf(pp - q), e2 = expf(u + kt - q);
        float ov = (e1 * a + e2 * vt) / (e1 * bb + e2);
        ks[tid * 66 + t] = (bf16_t)ov;
        float q2 = fmaxf(pp + wn, kt);
        float f1 = expf(pp + wn - q2), f2 = expf(kt - q2);
        a = f1 * a + f2 * vt;
        bb = f1 * bb + f2;
        pp = q2;
    }
    __syncthreads();
    for (int f = tid; f < 64 * 64; f += 64) {
        int cc = f >> 6, w = f & 63;
        outw[base + (size_t)cc * 4096 + w] = ks[cc * 66 + w];
    }
}

__global__ __launch_bounds__(256)
void wkv_v_kernel(const bf16_t* __restrict__ kin, const bf16_t* __restrict__ vin,
                  bf16_t* __restrict__ outw,
                  const float* __restrict__ decay, const float* __restrict__ first)
{
    int g = blockIdx.x * 256 + threadIdx.x;
    int w = g & 63;
    int c = (g >> 6) & 255;
    int b = g >> 14;
    size_t base = (size_t)(b * 256 + c) * 4096 + w;
    float u  = first[c];
    float wn = -expf(decay[c]);
    float a = 0.f, bb = 0.f, pp = -1e38f;
    for (int h = 0; h < 64; ++h) {
        size_t idx = base + h * 64;
        float kt = (float)kin[idx], vt = (float)vin[idx];
        float q  = fmaxf(pp, u + kt);
        float e1 = expf(pp - q), e2 = expf(u + kt - q);
        float ov = (e1 * a + e2 * vt) / (e1 * bb + e2);
        outw[idx] = (bf16_t)(0.5f * ((float)outw[idx] + ov));
        float q2 = fmaxf(pp + wn, kt);
        float f1 = expf(pp + wn - q2), f2 = expf(kt - q2);
        a = f1 * a + f2 * vt;
        bb = f1 * bb + f2;
        pp = q2;
    }
}

// ---------------------------------------------------------------------------
extern "C" void kernel_launch(void* const* d_in, const int* in_sizes, int n_in,
                              void* d_out, int out_size, void* d_ws, size_t ws_size,
                              hipStream_t stream)
{
    const float* x      = (const float*)d_in[0];
    const float* skip   = (const float*)d_in[1];
    const float* mask   = (const float*)d_in[2];
    const float* ln1_w  = (const float*)d_in[3];
    const float* ln1_b  = (const float*)d_in[4];
    const float* ln2_w  = (const float*)d_in[5];
    const float* ln2_b  = (const float*)d_in[6];
    const float* mix_k  = (const float*)d_in[7];
    const float* mix_v  = (const float*)d_in[8];
    const float* mix_r  = (const float*)d_in[9];
    const float* Wk     = (const float*)d_in[10];
    const float* Wv     = (const float*)d_in[11];
    const float* Wr     = (const float*)d_in[12];
    const float* Wo     = (const float*)d_in[13];
    const float* decay  = (const float*)d_in[14];
    const float* first  = (const float*)d_in[15];
    const float* kn_w   = (const float*)d_in[16];
    const float* kn_b   = (const float*)d_in[17];
    const float* sp_w   = (const float*)d_in[18];
    const float* sp_b   = (const float*)d_in[19];
    const float* c1_w   = (const float*)d_in[20];
    const float* c1_b   = (const float*)d_in[21];
    const float* bn1_g  = (const float*)d_in[22];
    const float* bn1_b  = (const float*)d_in[23];
    const float* c2_w   = (const float*)d_in[24];
    const float* c2_b   = (const float*)d_in[25];
    const float* bn2_g  = (const float*)d_in[26];
    const float* bn2_b  = (const float*)d_in[27];
    const float* c3_w   = (const float*)d_in[28];
    const float* c3_b   = (const float*)d_in[29];
    const float* bn3_g  = (const float*)d_in[30];
    const float* bn3_b  = (const float*)d_in[31];
    const float* up_w   = (const float*)d_in[32];
    const float* up_b   = (const float*)d_in[33];
    float* out = (float*)d_out;

    float* ws = (float*)d_ws;
    const size_t S = 8388608;
    const size_t Hs = S / 2;
    bf16_t* xk   = (bf16_t*)ws;
    bf16_t* xv   = (bf16_t*)(ws + Hs);
    bf16_t* xr   = (bf16_t*)(ws + 2 * Hs);
    bf16_t* kbuf = (bf16_t*)(ws + 3 * Hs);
    bf16_t* vbuf = (bf16_t*)(ws + 4 * Hs);
    bf16_t* rbuf = (bf16_t*)(ws + 5 * Hs);
    bf16_t* wkv  = (bf16_t*)(ws + 6 * Hs);
    bf16_t* xcat = (bf16_t*)(ws + 7 * Hs);          // TRANSPOSED [b][p][512]
    bf16_t* skbf = (bf16_t*)(ws + 9 * Hs);          // TRANSPOSED bf16 skip [b][p][512]
    bf16_t* y1   = (bf16_t*)(ws + 9 * Hs);          // TRANSPOSED y1 (reuses skbf)
    bf16_t* y2   = (bf16_t*)ws;                     // TRANSPOSED [b][p][1024]
    bf16_t* y3   = (bf16_t*)(ws + 4 * Hs);          // TRANSPOSED [b][p][256]
    float*  wtop = ws + 11 * Hs;
    bf16_t* w9   = (bf16_t*)wtop;
    bf16_t* wfl  = w9 + 1179648;
    float2* st1  = (float2*)(wfl + 1310720);
    float2* stk  = st1 + 32768;
    float2* st2  = stk + 32768;
    bf16_t* wkb = wfl;
    bf16_t* wob = wfl + 196608;
    bf16_t* c2b = wfl + 393216;
    bf16_t* c3b = wfl + 917504;
    bf16_t* upb = wfl + 1179648;

    dim3 blk(256);

    pack_all_kernel<<<dim3(9728), blk, 0, stream>>>(Wk, Wv, Wr, Wo, sp_w, c2_w,
                                                    c3_w, up_w, c1_w, wfl, w9);
    ln_stats_kernel<float, 0><<<dim3(512), blk, 0, stream>>>(x, st1);
    // skip -> bf16 transposed [b][p][512] (bit-identical rounding)
    skip_transpose_kernel<<<dim3(64, 8, 8), blk, 0, stream>>>(skip, skbf);

    qshift_mix_kernel<<<dim3(4096), blk, 0, stream>>>(x, st1, mask, ln1_w, ln1_b,
                                                      mix_k, mix_v, mix_r, xk, xv, xr);
    // k, v, sr in ONE launch
    mfma_gemm<1, 0, EP_KVR, 1, 64, 0><<<dim3(64, 4, 24), blk, 0, stream>>>(
        wkb, xk, nullptr, nullptr, nullptr, nullptr, nullptr, nullptr, nullptr,
        nullptr, nullptr, nullptr, nullptr, nullptr, kbuf, 256, 256, 256, 256, 0);
    // WKV scans
    wkv_h_kernel<<<dim3(4, 64, 8), dim3(64), 0, stream>>>(kbuf, vbuf, wkv, decay, first);
    wkv_v_kernel<<<dim3(512), blk, 0, stream>>>(kbuf, vbuf, wkv, decay, first);
    ln_stats_kernel<bf16_t, 0><<<dim3(512), blk, 0, stream>>>(wkv, stk);
    // MERGED woskip -> TRANSPOSED xcat (skip path reads transposed bf16)
    mfma_gemm<1, 3, EP_WOSKIP, 1, 64, 0><<<dim3(64, 4, 16), blk, 0, stream>>>(
        wob, wkv, rbuf, stk, kn_w, kn_b, sp_b, skbf, nullptr, nullptr,
        x, st1, ln1_w, ln1_b, xcat, 256, 0, 256, 512, 0);
    // grouped 3x3 conv (transposed in) -> TRANSPOSED y1
    mfma_gemm<3, 0, EP_GELU_BN, 1, 128, 1><<<dim3(32, 4, 8), blk, 0, stream>>>(
        w9, xcat, nullptr, nullptr, nullptr, nullptr, c1_b, nullptr, bn1_g, bn1_b,
        nullptr, nullptr, nullptr, nullptr, y1, 512, 256, 512, 512, 0);
    // c2 (transposed in) -> TRANSPOSED y2
    mfma_gemm<1, 4, EP_GELU_BN, 1, 128, 1><<<dim3(32, 8, 8), blk, 0, stream>>>(
        c2b, y1, nullptr, nullptr, nullptr, nullptr, c2_b, nullptr, bn2_g, bn2_b,
        nullptr, nullptr, nullptr, nullptr, y2, 1024, 512, 512, 1024, 0);
    // c3 (transposed in) -> TRANSPOSED y3
    mfma_gemm<1, 4, EP_GELU_BN, 1, 64, 1><<<dim3(64, 4, 8), blk, 0, stream>>>(
        c3b, y2, nullptr, nullptr, nullptr, nullptr, c3_b, nullptr, bn3_g, bn3_b,
        nullptr, nullptr, nullptr, nullptr, y3, 256, 1024, 1024, 256, 0);
    ln_stats_kernel<bf16_t, 1><<<dim3(512), blk, 0, stream>>>(y3, st2);
    // up-projection (transposed in + LN2 folded) + pixel shuffle -> out
    mfma_gemm<1, 5, EP_SHUFFLE, 0, 64, 0><<<dim3(64, 8, 8), blk, 0, stream>>>(
        upb, y3, nullptr, st2, ln2_w, ln2_b, up_b, nullptr, nullptr, nullptr,
        nullptr, nullptr, nullptr, nullptr, out, 512, 256, 256, 0, 0);
}